// Round 1
// baseline (6715.643 us; speedup 1.0000x reference)
//
#include <hip/hip_runtime.h>
#include <hip/hip_bf16.h>
#include <math.h>

#define N_EMBD 1024
#define N_HEADC 16
#define HEAD_D 64

// ---------------------------------------------------------------------------
// LayerNorm: one block (256 threads = 4 waves) per row of C=1024
// ---------------------------------------------------------------------------
__global__ void ln_kernel(const float* __restrict__ x,
                          const float* __restrict__ w,
                          const float* __restrict__ b,
                          float* __restrict__ out, int C) {
    const int row = blockIdx.x;
    const float* xr = x + (size_t)row * C;
    float s = 0.f, ss = 0.f;
    for (int i = threadIdx.x; i < C; i += blockDim.x) {
        float v = xr[i];
        s += v; ss += v * v;
    }
    // wave (64-lane) reduce
    for (int o = 32; o > 0; o >>= 1) {
        s  += __shfl_down(s, o);
        ss += __shfl_down(ss, o);
    }
    __shared__ float as_[4], ass_[4];
    const int wid = threadIdx.x >> 6, lane = threadIdx.x & 63;
    if (lane == 0) { as_[wid] = s; ass_[wid] = ss; }
    __syncthreads();
    if (threadIdx.x == 0) {
        float ts = 0.f, tss = 0.f;
        for (int i = 0; i < 4; i++) { ts += as_[i]; tss += ass_[i]; }
        as_[0] = ts; ass_[0] = tss;
    }
    __syncthreads();
    const float mu  = as_[0] / C;
    const float var = ass_[0] / C - mu * mu;
    const float inv = rsqrtf(var + 1e-5f);
    float* orow = out + (size_t)row * C;
    for (int i = threadIdx.x; i < C; i += blockDim.x) {
        orow[i] = (xr[i] - mu) * inv * w[i] + b[i];
    }
}

// ---------------------------------------------------------------------------
// FP32 LDS-tiled GEMM: out[M,N] = act(A[M,K] @ W[K,N] + bias[N]) (+ residual)
// BM=BN=64, BK=16, 256 threads, 4x4 accum per thread. All dims % 64 == 0.
// ---------------------------------------------------------------------------
#define BM 64
#define BN 64
#define BK 16

__global__ void gemm_kernel(const float* __restrict__ A,
                            const float* __restrict__ W,
                            const float* __restrict__ bias,
                            const float* __restrict__ residual,
                            float* __restrict__ out,
                            int M, int N, int K, int do_gelu) {
    __shared__ float As[BK][BM + 1];   // +1 pad: conflict-free transposed writes
    __shared__ float Ws[BK][BN + 1];

    const int tid = threadIdx.x;      // 0..255
    const int tx = tid & 15;          // 0..15 (n sub-index)
    const int ty = tid >> 4;          // 0..15 (m sub-index)
    const int bx = blockIdx.x;        // N tile
    const int by = blockIdx.y;        // M tile

    float acc[4][4];
#pragma unroll
    for (int i = 0; i < 4; i++)
#pragma unroll
        for (int j = 0; j < 4; j++) acc[i][j] = 0.f;

    for (int k0 = 0; k0 < K; k0 += BK) {
#pragma unroll
        for (int i = 0; i < 4; i++) {
            int idx = tid + i * 256;          // 0..1023
            int row = idx >> 4, col = idx & 15;
            As[col][row] = A[((size_t)(by * BM + row)) * K + (k0 + col)];
        }
#pragma unroll
        for (int i = 0; i < 4; i++) {
            int idx = tid + i * 256;
            int row = idx >> 6, col = idx & 63;
            Ws[row][col] = W[((size_t)(k0 + row)) * N + (bx * BN + col)];
        }
        __syncthreads();
#pragma unroll
        for (int kk = 0; kk < BK; kk++) {
            float a[4], w[4];
#pragma unroll
            for (int i = 0; i < 4; i++) a[i] = As[kk][ty + 16 * i];
#pragma unroll
            for (int j = 0; j < 4; j++) w[j] = Ws[kk][tx + 16 * j];
#pragma unroll
            for (int i = 0; i < 4; i++)
#pragma unroll
                for (int j = 0; j < 4; j++) acc[i][j] += a[i] * w[j];
        }
        __syncthreads();
    }

#pragma unroll
    for (int i = 0; i < 4; i++) {
#pragma unroll
        for (int j = 0; j < 4; j++) {
            const int m = by * BM + ty + 16 * i;
            const int n = bx * BN + tx + 16 * j;
            float v = acc[i][j] + bias[n];
            if (do_gelu) v = 0.5f * v * (1.f + erff(v * 0.70710678118654752f));
            if (residual) v += residual[(size_t)m * N + n];
            out[(size_t)m * N + n] = v;
        }
    }
}

// ---------------------------------------------------------------------------
// ALiBi causal attention, flash-style online softmax.
// One 64-lane wave per (b, h, q) row; lane = head-dim index d.
// qkv layout: [B, T, 3C] with q|k|v at col offsets 0|C|2C, head h at h*64.
// ---------------------------------------------------------------------------
__global__ void attn_kernel(const float* __restrict__ qkv,
                            float* __restrict__ y,
                            int B, int T) {
    const int C3 = 3 * N_EMBD;
    const int lane = threadIdx.x & 63;
    const int wave = blockIdx.x * (blockDim.x >> 6) + (threadIdx.x >> 6);
    const int q = wave % T;
    const int h = (wave / T) % N_HEADC;
    const int b = wave / (T * N_HEADC);

    const float scale = 0.125f;                   // 1/sqrt(64)
    const float slope = exp2f(-0.5f * (float)(h + 1));

    const size_t base = (size_t)b * T * C3;
    const float qd = qkv[base + (size_t)q * C3 + h * HEAD_D + lane] * scale;
    const float* kptr = qkv + base + N_EMBD     + h * HEAD_D + lane;
    const float* vptr = qkv + base + 2 * N_EMBD + h * HEAD_D + lane;

    float m = -INFINITY, l = 0.f, acc = 0.f;
    for (int k = 0; k <= q; k++) {
        float kv = kptr[(size_t)k * C3];
        float vv = vptr[(size_t)k * C3];
        float s = qd * kv;
#pragma unroll
        for (int o = 32; o > 0; o >>= 1) s += __shfl_xor(s, o);
        const float logit = s + slope * (float)(q - k);
        const float mn = fmaxf(m, logit);
        const float p = __expf(logit - mn);
        const float corr = __expf(m - mn);   // 0 on first iter (m = -inf)
        l = l * corr + p;
        acc = acc * corr + p * vv;
        m = mn;
    }
    y[((size_t)b * T + q) * N_EMBD + h * HEAD_D + lane] = acc / l;
}

// ---------------------------------------------------------------------------
extern "C" void kernel_launch(void* const* d_in, const int* in_sizes, int n_in,
                              void* d_out, int out_size, void* d_ws, size_t ws_size,
                              hipStream_t stream) {
    const int B = 2, T = 2048, C = N_EMBD;
    const int M = B * T;                 // 4096 rows

    const float* x      = (const float*)d_in[0];
    const float* ln1_w  = (const float*)d_in[1];
    const float* ln1_b  = (const float*)d_in[2];
    const float* w_qkv  = (const float*)d_in[3];
    const float* b_qkv  = (const float*)d_in[4];
    const float* w_proj = (const float*)d_in[5];
    const float* b_proj = (const float*)d_in[6];
    const float* ln2_w  = (const float*)d_in[7];
    const float* ln2_b  = (const float*)d_in[8];
    const float* w_fc   = (const float*)d_in[9];
    const float* b_fc   = (const float*)d_in[10];
    const float* w_fc2  = (const float*)d_in[11];
    const float* b_fc2  = (const float*)d_in[12];
    float* out = (float*)d_out;

    // workspace carve-up (bytes)
    char* ws = (char*)d_ws;
    float* buf_h   = (float*)(ws);                                   // 16 MB
    float* buf_qkv = (float*)(ws + (size_t)M * C * 4);               // 48 MB
    float* buf_y   = (float*)(ws + (size_t)M * C * 4 + (size_t)M * 3 * C * 4);  // 16 MB
    float* buf_fc  = (float*)(ws + (size_t)M * C * 4 * 2 + (size_t)M * 3 * C * 4); // 64 MB

    // 1. h = LN1(x)
    ln_kernel<<<M, 256, 0, stream>>>(x, ln1_w, ln1_b, buf_h, C);

    // 2. qkv = h @ w_qkv + b_qkv   [4096, 3072]
    gemm_kernel<<<dim3(3 * C / BN, M / BM), 256, 0, stream>>>(
        buf_h, w_qkv, b_qkv, nullptr, buf_qkv, M, 3 * C, C, 0);

    // 3. y = ALiBi-causal-attention(qkv)   [4096, 1024]
    {
        int waves = B * N_HEADC * T;         // 65536
        attn_kernel<<<waves / 4, 256, 0, stream>>>(buf_qkv, buf_y, B, T);
    }

    // 4. x1 = x + y @ w_proj + b_proj  -> d_out
    gemm_kernel<<<dim3(C / BN, M / BM), 256, 0, stream>>>(
        buf_y, w_proj, b_proj, x, out, M, C, C, 0);

    // 5. h = LN2(x1)
    ln_kernel<<<M, 256, 0, stream>>>(out, ln2_w, ln2_b, buf_h, C);

    // 6. fc = gelu(h @ w_fc + b_fc)   [4096, 4096]
    gemm_kernel<<<dim3(4 * C / BN, M / BM), 256, 0, stream>>>(
        buf_h, w_fc, b_fc, nullptr, buf_fc, M, 4 * C, C, 1);

    // 7. out = x1 + fc @ w_fc2 + b_fc2   (residual==out, same-index RMW: safe)
    gemm_kernel<<<dim3(C / BN, M / BM), 256, 0, stream>>>(
        buf_fc, w_fc2, b_fc2, out, out, M, C, 4 * C, 0);
}

// Round 2
// 2056.020 us; speedup vs baseline: 3.2663x; 3.2663x over previous
//
#include <hip/hip_runtime.h>
#include <hip/hip_bf16.h>
#include <math.h>

#define N_EMBD 1024
#define N_HEADC 16
#define HEAD_D 64

typedef __attribute__((ext_vector_type(8))) short short8;
typedef __attribute__((ext_vector_type(4))) float floatx4;

__device__ inline ushort f2b(float f) {
    __hip_bfloat16 h = __float2bfloat16(f);
    return *reinterpret_cast<ushort*>(&h);
}

// ---------------------------------------------------------------------------
// LayerNorm: one block (256 threads = 4 waves) per row of C=1024
// ---------------------------------------------------------------------------
__global__ void ln_kernel(const float* __restrict__ x,
                          const float* __restrict__ w,
                          const float* __restrict__ b,
                          float* __restrict__ out, int C) {
    const int row = blockIdx.x;
    const float* xr = x + (size_t)row * C;
    float s = 0.f, ss = 0.f;
    for (int i = threadIdx.x; i < C; i += blockDim.x) {
        float v = xr[i];
        s += v; ss += v * v;
    }
    for (int o = 32; o > 0; o >>= 1) {
        s  += __shfl_down(s, o);
        ss += __shfl_down(ss, o);
    }
    __shared__ float as_[4], ass_[4];
    const int wid = threadIdx.x >> 6, lane = threadIdx.x & 63;
    if (lane == 0) { as_[wid] = s; ass_[wid] = ss; }
    __syncthreads();
    if (threadIdx.x == 0) {
        float ts = 0.f, tss = 0.f;
        for (int i = 0; i < 4; i++) { ts += as_[i]; tss += ass_[i]; }
        as_[0] = ts; ass_[0] = tss;
    }
    __syncthreads();
    const float mu  = as_[0] / C;
    const float var = ass_[0] / C - mu * mu;
    const float inv = rsqrtf(var + 1e-5f);
    float* orow = out + (size_t)row * C;
    for (int i = threadIdx.x; i < C; i += blockDim.x) {
        orow[i] = (xr[i] - mu) * inv * w[i] + b[i];
    }
}

// ---------------------------------------------------------------------------
// FP32 LDS-tiled GEMM (unchanged this round; bf16 MFMA next round)
// ---------------------------------------------------------------------------
#define BM 64
#define BN 64
#define BK 16

__global__ void gemm_kernel(const float* __restrict__ A,
                            const float* __restrict__ W,
                            const float* __restrict__ bias,
                            const float* __restrict__ residual,
                            float* __restrict__ out,
                            int M, int N, int K, int do_gelu) {
    __shared__ float As[BK][BM + 1];
    __shared__ float Ws[BK][BN + 1];

    const int tid = threadIdx.x;
    const int tx = tid & 15;
    const int ty = tid >> 4;
    const int bx = blockIdx.x;
    const int by = blockIdx.y;

    float acc[4][4];
#pragma unroll
    for (int i = 0; i < 4; i++)
#pragma unroll
        for (int j = 0; j < 4; j++) acc[i][j] = 0.f;

    for (int k0 = 0; k0 < K; k0 += BK) {
#pragma unroll
        for (int i = 0; i < 4; i++) {
            int idx = tid + i * 256;
            int row = idx >> 4, col = idx & 15;
            As[col][row] = A[((size_t)(by * BM + row)) * K + (k0 + col)];
        }
#pragma unroll
        for (int i = 0; i < 4; i++) {
            int idx = tid + i * 256;
            int row = idx >> 6, col = idx & 63;
            Ws[row][col] = W[((size_t)(k0 + row)) * N + (bx * BN + col)];
        }
        __syncthreads();
#pragma unroll
        for (int kk = 0; kk < BK; kk++) {
            float a[4], w[4];
#pragma unroll
            for (int i = 0; i < 4; i++) a[i] = As[kk][ty + 16 * i];
#pragma unroll
            for (int j = 0; j < 4; j++) w[j] = Ws[kk][tx + 16 * j];
#pragma unroll
            for (int i = 0; i < 4; i++)
#pragma unroll
                for (int j = 0; j < 4; j++) acc[i][j] += a[i] * w[j];
        }
        __syncthreads();
    }

#pragma unroll
    for (int i = 0; i < 4; i++) {
#pragma unroll
        for (int j = 0; j < 4; j++) {
            const int m = by * BM + ty + 16 * i;
            const int n = bx * BN + tx + 16 * j;
            float v = acc[i][j] + bias[n];
            if (do_gelu) v = 0.5f * v * (1.f + erff(v * 0.70710678118654752f));
            if (residual) v += residual[(size_t)m * N + n];
            out[(size_t)m * N + n] = v;
        }
    }
}

// ---------------------------------------------------------------------------
// Flash-style ALiBi causal attention with bf16 MFMA (16x16x32).
// Block = 256 threads (4 waves), one 64-query tile per (b,h); loops kt<=qt.
// Layouts (HW-verified per guide):
//   A[m=lane&15][k=quad*8+j], B[k=quad*8+j][n=lane&15],
//   C/D: col=lane&15, row=quad*4+reg.
// Rows padded to 72 elems (144B): b128-aligned, 2-way-conflict only.
// ---------------------------------------------------------------------------
#define AT_PAD 72

__global__ __launch_bounds__(256) void attn_mfma_kernel(
        const float* __restrict__ qkv, float* __restrict__ y, int B, int T) {
    const int C3 = 3 * N_EMBD;
    const int qt = blockIdx.x;       // 0..T/64-1
    const int h  = blockIdx.y;
    const int b  = blockIdx.z;
    const int tid  = threadIdx.x;
    const int lane = tid & 63;
    const int w    = tid >> 6;       // wave 0..3
    const int quad = lane >> 4;
    const int l16  = lane & 15;

    __shared__ ushort Qs[64][AT_PAD];
    __shared__ ushort Ks[64][AT_PAD];
    __shared__ ushort Vt[64][AT_PAD];   // V transposed: Vt[d][k]
    __shared__ ushort Ps[64][AT_PAD];

    const float slope = exp2f(-0.5f * (float)(h + 1));
    const int q0 = qt * 64;
    const size_t hb = (size_t)b * T * C3 + (size_t)h * HEAD_D;

    // stage Q tile (pre-scaled by 1/sqrt(D); power-of-2, safe before bf16 cast)
#pragma unroll
    for (int i = 0; i < 4; i++) {
        int idx = tid + i * 256;
        int row = idx >> 4, d0 = (idx & 15) * 4;
        float4 qv = *(const float4*)&qkv[hb + (size_t)(q0 + row) * C3 + d0];
        ushort4 u;
        u.x = f2b(qv.x * 0.125f); u.y = f2b(qv.y * 0.125f);
        u.z = f2b(qv.z * 0.125f); u.w = f2b(qv.w * 0.125f);
        *(ushort4*)&Qs[row][d0] = u;
    }

    float m_r[4], l_r[4];
    floatx4 acc[4];
#pragma unroll
    for (int r = 0; r < 4; r++) {
        m_r[r] = -INFINITY; l_r[r] = 0.f;
        acc[r] = (floatx4){0.f, 0.f, 0.f, 0.f};
    }

    for (int kt = 0; kt <= qt; kt++) {
        // ---- stage K (row-major) and V (transposed) as bf16 ----
#pragma unroll
        for (int i = 0; i < 4; i++) {
            int idx = tid + i * 256;
            int row = idx >> 4, d0 = (idx & 15) * 4;
            const size_t src = hb + (size_t)(kt * 64 + row) * C3 + d0;
            float4 kv = *(const float4*)&qkv[src + N_EMBD];
            ushort4 u;
            u.x = f2b(kv.x); u.y = f2b(kv.y); u.z = f2b(kv.z); u.w = f2b(kv.w);
            *(ushort4*)&Ks[row][d0] = u;
            float4 vv = *(const float4*)&qkv[src + 2 * N_EMBD];
            Vt[d0 + 0][row] = f2b(vv.x);
            Vt[d0 + 1][row] = f2b(vv.y);
            Vt[d0 + 2][row] = f2b(vv.z);
            Vt[d0 + 3][row] = f2b(vv.w);
        }
        __syncthreads();

        // ---- scores: S[16q x 64k] per wave via MFMA ----
        const int mrow = w * 16 + l16;
        short8 aq0 = *(const short8*)&Qs[mrow][quad * 8];
        short8 aq1 = *(const short8*)&Qs[mrow][32 + quad * 8];
        floatx4 sfrag[4];
#pragma unroll
        for (int kb = 0; kb < 4; kb++) {
            int kcol = kb * 16 + l16;
            short8 bk0 = *(const short8*)&Ks[kcol][quad * 8];
            short8 bk1 = *(const short8*)&Ks[kcol][32 + quad * 8];
            floatx4 s = (floatx4){0.f, 0.f, 0.f, 0.f};
            s = __builtin_amdgcn_mfma_f32_16x16x32_bf16(aq0, bk0, s, 0, 0, 0);
            s = __builtin_amdgcn_mfma_f32_16x16x32_bf16(aq1, bk1, s, 0, 0, 0);
            sfrag[kb] = s;
        }

        // ---- ALiBi bias + causal mask + online softmax ----
#pragma unroll
        for (int r = 0; r < 4; r++) {
            const int q = q0 + w * 16 + quad * 4 + r;
            float sv[4];
            float rm = -INFINITY;
#pragma unroll
            for (int kb = 0; kb < 4; kb++) {
                int k = kt * 64 + kb * 16 + l16;
                float s = sfrag[kb][r];
                s = (k <= q) ? (s + slope * (float)(q - k)) : -INFINITY;
                sv[kb] = s;
                rm = fmaxf(rm, s);
            }
#pragma unroll
            for (int o = 8; o >= 1; o >>= 1) rm = fmaxf(rm, __shfl_xor(rm, o));
            const float mnew = fmaxf(m_r[r], rm);
            const float corr = __expf(m_r[r] - mnew);
            float rs = 0.f;
#pragma unroll
            for (int kb = 0; kb < 4; kb++) {
                float pv = __expf(sv[kb] - mnew);
                rs += pv;
                Ps[w * 16 + quad * 4 + r][kb * 16 + l16] = f2b(pv);
            }
#pragma unroll
            for (int o = 8; o >= 1; o >>= 1) rs += __shfl_xor(rs, o);
            l_r[r] = l_r[r] * corr + rs;
            m_r[r] = mnew;
#pragma unroll
            for (int db = 0; db < 4; db++) acc[db][r] *= corr;
        }
        __syncthreads();

        // ---- PV: O[16q x 64d] += P @ V ----
        short8 ap0 = *(const short8*)&Ps[w * 16 + l16][quad * 8];
        short8 ap1 = *(const short8*)&Ps[w * 16 + l16][32 + quad * 8];
#pragma unroll
        for (int db = 0; db < 4; db++) {
            short8 bv0 = *(const short8*)&Vt[db * 16 + l16][quad * 8];
            short8 bv1 = *(const short8*)&Vt[db * 16 + l16][32 + quad * 8];
            acc[db] = __builtin_amdgcn_mfma_f32_16x16x32_bf16(ap0, bv0, acc[db], 0, 0, 0);
            acc[db] = __builtin_amdgcn_mfma_f32_16x16x32_bf16(ap1, bv1, acc[db], 0, 0, 0);
        }
        __syncthreads();
    }

    // ---- epilogue: O /= l, write y[b,t,h,d] ----
#pragma unroll
    for (int r = 0; r < 4; r++) {
        const int q = q0 + w * 16 + quad * 4 + r;
        const float invl = 1.f / l_r[r];
#pragma unroll
        for (int db = 0; db < 4; db++) {
            y[((size_t)b * T + q) * N_EMBD + h * HEAD_D + db * 16 + l16] =
                acc[db][r] * invl;
        }
    }
}

// ---------------------------------------------------------------------------
extern "C" void kernel_launch(void* const* d_in, const int* in_sizes, int n_in,
                              void* d_out, int out_size, void* d_ws, size_t ws_size,
                              hipStream_t stream) {
    const int B = 2, T = 2048, C = N_EMBD;
    const int M = B * T;

    const float* x      = (const float*)d_in[0];
    const float* ln1_w  = (const float*)d_in[1];
    const float* ln1_b  = (const float*)d_in[2];
    const float* w_qkv  = (const float*)d_in[3];
    const float* b_qkv  = (const float*)d_in[4];
    const float* w_proj = (const float*)d_in[5];
    const float* b_proj = (const float*)d_in[6];
    const float* ln2_w  = (const float*)d_in[7];
    const float* ln2_b  = (const float*)d_in[8];
    const float* w_fc   = (const float*)d_in[9];
    const float* b_fc   = (const float*)d_in[10];
    const float* w_fc2  = (const float*)d_in[11];
    const float* b_fc2  = (const float*)d_in[12];
    float* out = (float*)d_out;

    char* ws = (char*)d_ws;
    float* buf_h   = (float*)(ws);
    float* buf_qkv = (float*)(ws + (size_t)M * C * 4);
    float* buf_y   = (float*)(ws + (size_t)M * C * 4 + (size_t)M * 3 * C * 4);
    float* buf_fc  = (float*)(ws + (size_t)M * C * 4 * 2 + (size_t)M * 3 * C * 4);

    // 1. h = LN1(x)
    ln_kernel<<<M, 256, 0, stream>>>(x, ln1_w, ln1_b, buf_h, C);

    // 2. qkv = h @ w_qkv + b_qkv
    gemm_kernel<<<dim3(3 * C / BN, M / BM), 256, 0, stream>>>(
        buf_h, w_qkv, b_qkv, nullptr, buf_qkv, M, 3 * C, C, 0);

    // 3. y = flash ALiBi attention (MFMA)
    attn_mfma_kernel<<<dim3(T / 64, N_HEADC, B), 256, 0, stream>>>(
        buf_qkv, buf_y, B, T);

    // 4. x1 = x + y @ w_proj + b_proj
    gemm_kernel<<<dim3(C / BN, M / BM), 256, 0, stream>>>(
        buf_y, w_proj, b_proj, x, out, M, C, C, 0);

    // 5. h = LN2(x1)
    ln_kernel<<<M, 256, 0, stream>>>(out, ln2_w, ln2_b, buf_h, C);

    // 6. fc = gelu(h @ w_fc + b_fc)
    gemm_kernel<<<dim3(4 * C / BN, M / BM), 256, 0, stream>>>(
        buf_h, w_fc, b_fc, nullptr, buf_fc, M, 4 * C, C, 1);

    // 7. out = x1 + fc @ w_fc2 + b_fc2
    gemm_kernel<<<dim3(C / BN, M / BM), 256, 0, stream>>>(
        buf_fc, w_fc2, b_fc2, out, out, M, C, 4 * C, 0);
}

// Round 3
// 577.355 us; speedup vs baseline: 11.6317x; 3.5611x over previous
//
#include <hip/hip_runtime.h>
#include <hip/hip_bf16.h>
#include <math.h>

#define N_EMBD 1024
#define N_HEADC 16
#define HEAD_D 64

typedef __attribute__((ext_vector_type(8))) short short8;
typedef __attribute__((ext_vector_type(4))) float floatx4;

__device__ __forceinline__ ushort f2b(float f) {
    __hip_bfloat16 h = __float2bfloat16(f);
    return *reinterpret_cast<ushort*>(&h);
}

__device__ __forceinline__ void async_cp16(const void* gsrc, void* ldst) {
    __builtin_amdgcn_global_load_lds(
        (const __attribute__((address_space(1))) void*)gsrc,
        (__attribute__((address_space(3))) void*)ldst, 16, 0, 0);
}

// ---------------------------------------------------------------------------
// LayerNorm: fp32 in, bf16 out. One block (256 thr) per row of C=1024.
// ---------------------------------------------------------------------------
__global__ void ln_kernel(const float* __restrict__ x,
                          const float* __restrict__ w,
                          const float* __restrict__ b,
                          ushort* __restrict__ out, int C) {
    const int row = blockIdx.x;
    const float* xr = x + (size_t)row * C;
    float s = 0.f, ss = 0.f;
    for (int i = threadIdx.x; i < C; i += blockDim.x) {
        float v = xr[i];
        s += v; ss += v * v;
    }
    for (int o = 32; o > 0; o >>= 1) {
        s  += __shfl_down(s, o);
        ss += __shfl_down(ss, o);
    }
    __shared__ float as_[4], ass_[4];
    const int wid = threadIdx.x >> 6, lane = threadIdx.x & 63;
    if (lane == 0) { as_[wid] = s; ass_[wid] = ss; }
    __syncthreads();
    if (threadIdx.x == 0) {
        float ts = 0.f, tss = 0.f;
        for (int i = 0; i < 4; i++) { ts += as_[i]; tss += ass_[i]; }
        as_[0] = ts; ass_[0] = tss;
    }
    __syncthreads();
    const float mu  = as_[0] / C;
    const float var = ass_[0] / C - mu * mu;
    const float inv = rsqrtf(var + 1e-5f);
    ushort* orow = out + (size_t)row * C;
    for (int i = threadIdx.x; i < C; i += blockDim.x) {
        orow[i] = f2b((xr[i] - mu) * inv * w[i] + b[i]);
    }
}

// ---------------------------------------------------------------------------
// Transpose + convert: W[K,N] fp32 -> Wt[N,K] bf16. 32x32 tiles, 256 thr.
// grid = (N/32, K/32)
// ---------------------------------------------------------------------------
__global__ void convtrans_kernel(const float* __restrict__ W,
                                 ushort* __restrict__ Wt, int K, int N) {
    __shared__ float tile[32][33];
    const int tid = threadIdx.x;
    const int r = tid >> 3;          // 0..31
    const int c4 = (tid & 7) * 4;    // 0,4,..,28
    const int bx = blockIdx.x, by = blockIdx.y;

    float4 v = *(const float4*)&W[((size_t)(by * 32 + r)) * N + bx * 32 + c4];
    tile[r][c4 + 0] = v.x; tile[r][c4 + 1] = v.y;
    tile[r][c4 + 2] = v.z; tile[r][c4 + 3] = v.w;
    __syncthreads();

    // write along K: n = bx*32 + r, k = by*32 + c4..c4+3
    ushort4 u;
    u.x = f2b(tile[c4 + 0][r]); u.y = f2b(tile[c4 + 1][r]);
    u.z = f2b(tile[c4 + 2][r]); u.w = f2b(tile[c4 + 3][r]);
    *(ushort4*)&Wt[((size_t)(bx * 32 + r)) * K + by * 32 + c4] = u;
}

// ---------------------------------------------------------------------------
// bf16 MFMA GEMM (m97 structure): out = act(A @ Wt^T + bias) (+ residual)
// A[M,K] bf16 row-major, Wt[N,K] bf16 row-major (i.e. W^T).
// 128x128 tile, BK=32, 256 thr = 4 waves (2x2), each wave 64x64 out
// via 4x4 grid of mfma_f32_16x16x32_bf16. global_load_lds width-16 staging.
// ---------------------------------------------------------------------------
__global__ __launch_bounds__(256) void gemm_bf16_kernel(
        const ushort* __restrict__ A,
        const ushort* __restrict__ Bt,
        const float* __restrict__ bias,
        const float* __restrict__ residual,
        float* __restrict__ out32,
        ushort* __restrict__ out16,
        int M, int N, int K, int do_gelu) {
    __shared__ ushort As[128 * 32];   // [row][k] contiguous (global_load_lds)
    __shared__ ushort Bs[128 * 32];   // [n][k] contiguous

    const int tid  = threadIdx.x;
    const int w    = tid >> 6;
    const int lane = tid & 63;
    const int quad = lane >> 4;
    const int l16  = lane & 15;
    const int wm   = w >> 1;          // 0..1
    const int wn   = w & 1;           // 0..1
    const int m0   = blockIdx.y * 128;
    const int n0   = blockIdx.x * 128;

    floatx4 acc[4][4];
#pragma unroll
    for (int i = 0; i < 4; i++)
#pragma unroll
        for (int j = 0; j < 4; j++) acc[i][j] = (floatx4){0.f, 0.f, 0.f, 0.f};

    for (int k0 = 0; k0 < K; k0 += 32) {
        // ---- stage A,B tiles: 512 16B-chunks each; 2 per thread per tile ----
#pragma unroll
        for (int l = 0; l < 2; l++) {
            const int cbase = w * 128 + l * 64;      // wave-uniform chunk base
            const int c = cbase + lane;
            const int row = c >> 2, kc8 = (c & 3) * 8;
            async_cp16(A  + (size_t)(m0 + row) * K + k0 + kc8, &As[cbase * 8]);
            async_cp16(Bt + (size_t)(n0 + row) * K + k0 + kc8, &Bs[cbase * 8]);
        }
        __syncthreads();

        // ---- MFMA: 16 per wave per K-step ----
        short8 a[4], bf[4];
#pragma unroll
        for (int i = 0; i < 4; i++)
            a[i] = *(const short8*)&As[(wm * 64 + i * 16 + l16) * 32 + quad * 8];
#pragma unroll
        for (int j = 0; j < 4; j++)
            bf[j] = *(const short8*)&Bs[(wn * 64 + j * 16 + l16) * 32 + quad * 8];
#pragma unroll
        for (int i = 0; i < 4; i++)
#pragma unroll
            for (int j = 0; j < 4; j++)
                acc[i][j] = __builtin_amdgcn_mfma_f32_16x16x32_bf16(
                    a[i], bf[j], acc[i][j], 0, 0, 0);
        __syncthreads();
    }

    // ---- epilogue: C-layout col=l16, row=quad*4+r ----
#pragma unroll
    for (int i = 0; i < 4; i++) {
#pragma unroll
        for (int j = 0; j < 4; j++) {
            const int nn = n0 + wn * 64 + j * 16 + l16;
            const float bv = bias[nn];
#pragma unroll
            for (int r = 0; r < 4; r++) {
                const int mm = m0 + wm * 64 + i * 16 + quad * 4 + r;
                float v = acc[i][j][r] + bv;
                if (do_gelu) v = 0.5f * v * (1.f + erff(v * 0.70710678118654752f));
                if (residual) v += residual[(size_t)mm * N + nn];
                if (out32) out32[(size_t)mm * N + nn] = v;
                if (out16) out16[(size_t)mm * N + nn] = f2b(v);
            }
        }
    }
}

// ---------------------------------------------------------------------------
// Flash-style ALiBi causal attention, bf16 in/out, bf16 MFMA 16x16x32.
// Block = 256 thr (4 waves), one 64-query tile per (b,h); loops kt<=qt.
// ---------------------------------------------------------------------------
#define AT_PAD 72

__global__ __launch_bounds__(256) void attn_mfma_kernel(
        const ushort* __restrict__ qkv, ushort* __restrict__ y, int B, int T) {
    const int C3 = 3 * N_EMBD;
    const int qt = blockIdx.x;
    const int h  = blockIdx.y;
    const int b  = blockIdx.z;
    const int tid  = threadIdx.x;
    const int lane = tid & 63;
    const int w    = tid >> 6;
    const int quad = lane >> 4;
    const int l16  = lane & 15;

    __shared__ ushort Qs[64][AT_PAD];
    __shared__ ushort Ks[64][AT_PAD];
    __shared__ ushort Vt[64][AT_PAD];   // V transposed: Vt[d][k]
    __shared__ ushort Ps[64][AT_PAD];

    const float slope = exp2f(-0.5f * (float)(h + 1));
    const int q0 = qt * 64;
    const size_t hb = (size_t)b * T * C3 + (size_t)h * HEAD_D;

    // stage Q tile (raw bf16 copy; 1/sqrt(D) folded into logits)
#pragma unroll
    for (int i = 0; i < 4; i++) {
        int idx = tid + i * 256;
        int row = idx >> 4, d0 = (idx & 15) * 4;
        *(ushort4*)&Qs[row][d0] =
            *(const ushort4*)&qkv[hb + (size_t)(q0 + row) * C3 + d0];
    }

    float m_r[4], l_r[4];
    floatx4 acc[4];
#pragma unroll
    for (int r = 0; r < 4; r++) {
        m_r[r] = -INFINITY; l_r[r] = 0.f;
        acc[r] = (floatx4){0.f, 0.f, 0.f, 0.f};
    }

    for (int kt = 0; kt <= qt; kt++) {
        // ---- stage K (row-major) and V (transposed) ----
#pragma unroll
        for (int i = 0; i < 4; i++) {
            int idx = tid + i * 256;
            int row = idx >> 4, d0 = (idx & 15) * 4;
            const size_t src = hb + (size_t)(kt * 64 + row) * C3 + d0;
            *(ushort4*)&Ks[row][d0] = *(const ushort4*)&qkv[src + N_EMBD];
            ushort4 vv = *(const ushort4*)&qkv[src + 2 * N_EMBD];
            Vt[d0 + 0][row] = vv.x;
            Vt[d0 + 1][row] = vv.y;
            Vt[d0 + 2][row] = vv.z;
            Vt[d0 + 3][row] = vv.w;
        }
        __syncthreads();

        // ---- scores: S[16q x 64k] per wave ----
        const int mrow = w * 16 + l16;
        short8 aq0 = *(const short8*)&Qs[mrow][quad * 8];
        short8 aq1 = *(const short8*)&Qs[mrow][32 + quad * 8];
        floatx4 sfrag[4];
#pragma unroll
        for (int kb = 0; kb < 4; kb++) {
            int kcol = kb * 16 + l16;
            short8 bk0 = *(const short8*)&Ks[kcol][quad * 8];
            short8 bk1 = *(const short8*)&Ks[kcol][32 + quad * 8];
            floatx4 s = (floatx4){0.f, 0.f, 0.f, 0.f};
            s = __builtin_amdgcn_mfma_f32_16x16x32_bf16(aq0, bk0, s, 0, 0, 0);
            s = __builtin_amdgcn_mfma_f32_16x16x32_bf16(aq1, bk1, s, 0, 0, 0);
            sfrag[kb] = s;
        }

        // ---- ALiBi + causal mask + online softmax ----
#pragma unroll
        for (int r = 0; r < 4; r++) {
            const int q = q0 + w * 16 + quad * 4 + r;
            float sv[4];
            float rm = -INFINITY;
#pragma unroll
            for (int kb = 0; kb < 4; kb++) {
                int k = kt * 64 + kb * 16 + l16;
                float s = sfrag[kb][r] * 0.125f;
                s = (k <= q) ? (s + slope * (float)(q - k)) : -INFINITY;
                sv[kb] = s;
                rm = fmaxf(rm, s);
            }
#pragma unroll
            for (int o = 8; o >= 1; o >>= 1) rm = fmaxf(rm, __shfl_xor(rm, o));
            const float mnew = fmaxf(m_r[r], rm);
            const float corr = __expf(m_r[r] - mnew);
            float rs = 0.f;
#pragma unroll
            for (int kb = 0; kb < 4; kb++) {
                float pv = __expf(sv[kb] - mnew);
                rs += pv;
                Ps[w * 16 + quad * 4 + r][kb * 16 + l16] = f2b(pv);
            }
#pragma unroll
            for (int o = 8; o >= 1; o >>= 1) rs += __shfl_xor(rs, o);
            l_r[r] = l_r[r] * corr + rs;
            m_r[r] = mnew;
#pragma unroll
            for (int db = 0; db < 4; db++) acc[db][r] *= corr;
        }
        __syncthreads();

        // ---- PV ----
        short8 ap0 = *(const short8*)&Ps[w * 16 + l16][quad * 8];
        short8 ap1 = *(const short8*)&Ps[w * 16 + l16][32 + quad * 8];
#pragma unroll
        for (int db = 0; db < 4; db++) {
            short8 bv0 = *(const short8*)&Vt[db * 16 + l16][quad * 8];
            short8 bv1 = *(const short8*)&Vt[db * 16 + l16][32 + quad * 8];
            acc[db] = __builtin_amdgcn_mfma_f32_16x16x32_bf16(ap0, bv0, acc[db], 0, 0, 0);
            acc[db] = __builtin_amdgcn_mfma_f32_16x16x32_bf16(ap1, bv1, acc[db], 0, 0, 0);
        }
        __syncthreads();
    }

    // ---- epilogue: O /= l, write y bf16 ----
#pragma unroll
    for (int r = 0; r < 4; r++) {
        const int q = q0 + w * 16 + quad * 4 + r;
        const float invl = 1.f / l_r[r];
#pragma unroll
        for (int db = 0; db < 4; db++) {
            y[((size_t)b * T + q) * N_EMBD + h * HEAD_D + db * 16 + l16] =
                f2b(acc[db][r] * invl);
        }
    }
}

// ---------------------------------------------------------------------------
extern "C" void kernel_launch(void* const* d_in, const int* in_sizes, int n_in,
                              void* d_out, int out_size, void* d_ws, size_t ws_size,
                              hipStream_t stream) {
    const int B = 2, T = 2048, C = N_EMBD;
    const int M = B * T;

    const float* x      = (const float*)d_in[0];
    const float* ln1_w  = (const float*)d_in[1];
    const float* ln1_b  = (const float*)d_in[2];
    const float* w_qkv  = (const float*)d_in[3];
    const float* b_qkv  = (const float*)d_in[4];
    const float* w_proj = (const float*)d_in[5];
    const float* b_proj = (const float*)d_in[6];
    const float* ln2_w  = (const float*)d_in[7];
    const float* ln2_b  = (const float*)d_in[8];
    const float* w_fc   = (const float*)d_in[9];
    const float* b_fc   = (const float*)d_in[10];
    const float* w_fc2  = (const float*)d_in[11];
    const float* b_fc2  = (const float*)d_in[12];
    float* out = (float*)d_out;

    // workspace carve-up (bf16 buffers)
    char* ws = (char*)d_ws;
    size_t off = 0;
    ushort* wt_qkv  = (ushort*)(ws + off); off += (size_t)3 * C * C * 2;   // 6 MB
    ushort* wt_proj = (ushort*)(ws + off); off += (size_t)C * C * 2;       // 2 MB
    ushort* wt_fc   = (ushort*)(ws + off); off += (size_t)4 * C * C * 2;   // 8 MB
    ushort* wt_fc2  = (ushort*)(ws + off); off += (size_t)4 * C * C * 2;   // 8 MB
    ushort* h16     = (ushort*)(ws + off); off += (size_t)M * C * 2;       // 8 MB
    ushort* qkv16   = (ushort*)(ws + off); off += (size_t)M * 3 * C * 2;   // 24 MB
    ushort* y16     = (ushort*)(ws + off); off += (size_t)M * C * 2;       // 8 MB
    ushort* fc16    = (ushort*)(ws + off); off += (size_t)M * 4 * C * 2;   // 32 MB

    // 0. weight transpose+convert (fp32 [K,N] -> bf16 [N,K])
    convtrans_kernel<<<dim3(3 * C / 32, C / 32), 256, 0, stream>>>(w_qkv, wt_qkv, C, 3 * C);
    convtrans_kernel<<<dim3(C / 32, C / 32), 256, 0, stream>>>(w_proj, wt_proj, C, C);
    convtrans_kernel<<<dim3(4 * C / 32, C / 32), 256, 0, stream>>>(w_fc, wt_fc, C, 4 * C);
    convtrans_kernel<<<dim3(C / 32, 4 * C / 32), 256, 0, stream>>>(w_fc2, wt_fc2, 4 * C, C);

    // 1. h = LN1(x) -> bf16
    ln_kernel<<<M, 256, 0, stream>>>(x, ln1_w, ln1_b, h16, C);

    // 2. qkv = h @ w_qkv + b_qkv -> bf16 only
    gemm_bf16_kernel<<<dim3(3 * C / 128, M / 128), 256, 0, stream>>>(
        h16, wt_qkv, b_qkv, nullptr, nullptr, qkv16, M, 3 * C, C, 0);

    // 3. y = flash ALiBi attention -> bf16
    attn_mfma_kernel<<<dim3(T / 64, N_HEADC, B), 256, 0, stream>>>(
        qkv16, y16, B, T);

    // 4. x1 = x + y @ w_proj + b_proj -> d_out (fp32)
    gemm_bf16_kernel<<<dim3(C / 128, M / 128), 256, 0, stream>>>(
        y16, wt_proj, b_proj, x, out, nullptr, M, C, C, 0);

    // 5. h = LN2(x1) -> bf16
    ln_kernel<<<M, 256, 0, stream>>>(out, ln2_w, ln2_b, h16, C);

    // 6. fc = gelu(h @ w_fc + b_fc) -> bf16 only
    gemm_bf16_kernel<<<dim3(4 * C / 128, M / 128), 256, 0, stream>>>(
        h16, wt_fc, b_fc, nullptr, nullptr, fc16, M, 4 * C, C, 1);

    // 7. out = x1 + fc @ w_fc2 + b_fc2 -> d_out (fp32, same-index RMW safe)
    gemm_bf16_kernel<<<dim3(C / 128, M / 128), 256, 0, stream>>>(
        fc16, wt_fc2, b_fc2, out, out, nullptr, M, C, 4 * C, 0);
}

// Round 4
// 514.771 us; speedup vs baseline: 13.0459x; 1.1216x over previous
//
#include <hip/hip_runtime.h>
#include <hip/hip_bf16.h>
#include <math.h>

#define N_EMBD 1024
#define N_HEADC 16
#define HEAD_D 64

typedef __attribute__((ext_vector_type(8))) short short8;
typedef __attribute__((ext_vector_type(4))) float floatx4;

__device__ __forceinline__ ushort f2b(float f) {
    __hip_bfloat16 h = __float2bfloat16(f);
    return *reinterpret_cast<ushort*>(&h);
}

__device__ __forceinline__ void async_cp16(const void* gsrc, void* ldst) {
    __builtin_amdgcn_global_load_lds(
        (const __attribute__((address_space(1))) void*)gsrc,
        (__attribute__((address_space(3))) void*)ldst, 16, 0, 0);
}

// ---------------------------------------------------------------------------
// LayerNorm: fp32 in, bf16 out. One block (256 thr) per row of C=1024.
// ---------------------------------------------------------------------------
__global__ void ln_kernel(const float* __restrict__ x,
                          const float* __restrict__ w,
                          const float* __restrict__ b,
                          ushort* __restrict__ out, int C) {
    const int row = blockIdx.x;
    const float* xr = x + (size_t)row * C;
    float s = 0.f, ss = 0.f;
    for (int i = threadIdx.x; i < C; i += blockDim.x) {
        float v = xr[i];
        s += v; ss += v * v;
    }
    for (int o = 32; o > 0; o >>= 1) {
        s  += __shfl_down(s, o);
        ss += __shfl_down(ss, o);
    }
    __shared__ float as_[4], ass_[4];
    const int wid = threadIdx.x >> 6, lane = threadIdx.x & 63;
    if (lane == 0) { as_[wid] = s; ass_[wid] = ss; }
    __syncthreads();
    if (threadIdx.x == 0) {
        float ts = 0.f, tss = 0.f;
        for (int i = 0; i < 4; i++) { ts += as_[i]; tss += ass_[i]; }
        as_[0] = ts; ass_[0] = tss;
    }
    __syncthreads();
    const float mu  = as_[0] / C;
    const float var = ass_[0] / C - mu * mu;
    const float inv = rsqrtf(var + 1e-5f);
    ushort* orow = out + (size_t)row * C;
    for (int i = threadIdx.x; i < C; i += blockDim.x) {
        orow[i] = f2b((xr[i] - mu) * inv * w[i] + b[i]);
    }
}

// ---------------------------------------------------------------------------
// Transpose + convert: W[K,N] fp32 -> Wt[N,K] bf16. 32x32 tiles, 256 thr.
// ---------------------------------------------------------------------------
__global__ void convtrans_kernel(const float* __restrict__ W,
                                 ushort* __restrict__ Wt, int K, int N) {
    __shared__ float tile[32][33];
    const int tid = threadIdx.x;
    const int r = tid >> 3;
    const int c4 = (tid & 7) * 4;
    const int bx = blockIdx.x, by = blockIdx.y;

    float4 v = *(const float4*)&W[((size_t)(by * 32 + r)) * N + bx * 32 + c4];
    tile[r][c4 + 0] = v.x; tile[r][c4 + 1] = v.y;
    tile[r][c4 + 2] = v.z; tile[r][c4 + 3] = v.w;
    __syncthreads();

    ushort4 u;
    u.x = f2b(tile[c4 + 0][r]); u.y = f2b(tile[c4 + 1][r]);
    u.z = f2b(tile[c4 + 2][r]); u.w = f2b(tile[c4 + 3][r]);
    *(ushort4*)&Wt[((size_t)(bx * 32 + r)) * K + by * 32 + c4] = u;
}

// ---------------------------------------------------------------------------
// bf16 MFMA GEMM (m97 structure), unchanged from R2.
// ---------------------------------------------------------------------------
__global__ __launch_bounds__(256) void gemm_bf16_kernel(
        const ushort* __restrict__ A,
        const ushort* __restrict__ Bt,
        const float* __restrict__ bias,
        const float* __restrict__ residual,
        float* __restrict__ out32,
        ushort* __restrict__ out16,
        int M, int N, int K, int do_gelu) {
    __shared__ ushort As[128 * 32];
    __shared__ ushort Bs[128 * 32];

    const int tid  = threadIdx.x;
    const int w    = tid >> 6;
    const int lane = tid & 63;
    const int quad = lane >> 4;
    const int l16  = lane & 15;
    const int wm   = w >> 1;
    const int wn   = w & 1;
    const int m0   = blockIdx.y * 128;
    const int n0   = blockIdx.x * 128;

    floatx4 acc[4][4];
#pragma unroll
    for (int i = 0; i < 4; i++)
#pragma unroll
        for (int j = 0; j < 4; j++) acc[i][j] = (floatx4){0.f, 0.f, 0.f, 0.f};

    for (int k0 = 0; k0 < K; k0 += 32) {
#pragma unroll
        for (int l = 0; l < 2; l++) {
            const int cbase = w * 128 + l * 64;
            const int c = cbase + lane;
            const int row = c >> 2, kc8 = (c & 3) * 8;
            async_cp16(A  + (size_t)(m0 + row) * K + k0 + kc8, &As[cbase * 8]);
            async_cp16(Bt + (size_t)(n0 + row) * K + k0 + kc8, &Bs[cbase * 8]);
        }
        __syncthreads();

        short8 a[4], bf[4];
#pragma unroll
        for (int i = 0; i < 4; i++)
            a[i] = *(const short8*)&As[(wm * 64 + i * 16 + l16) * 32 + quad * 8];
#pragma unroll
        for (int j = 0; j < 4; j++)
            bf[j] = *(const short8*)&Bs[(wn * 64 + j * 16 + l16) * 32 + quad * 8];
#pragma unroll
        for (int i = 0; i < 4; i++)
#pragma unroll
            for (int j = 0; j < 4; j++)
                acc[i][j] = __builtin_amdgcn_mfma_f32_16x16x32_bf16(
                    a[i], bf[j], acc[i][j], 0, 0, 0);
        __syncthreads();
    }

#pragma unroll
    for (int i = 0; i < 4; i++) {
#pragma unroll
        for (int j = 0; j < 4; j++) {
            const int nn = n0 + wn * 64 + j * 16 + l16;
            const float bv = bias[nn];
#pragma unroll
            for (int r = 0; r < 4; r++) {
                const int mm = m0 + wm * 64 + i * 16 + quad * 4 + r;
                float v = acc[i][j][r] + bv;
                if (do_gelu) v = 0.5f * v * (1.f + erff(v * 0.70710678118654752f));
                if (residual) v += residual[(size_t)mm * N + nn];
                if (out32) out32[(size_t)mm * N + nn] = v;
                if (out16) out16[(size_t)mm * N + nn] = f2b(v);
            }
        }
    }
}

// ---------------------------------------------------------------------------
// Flash ALiBi attention, triangle-paired: block handles q-tiles p and 31-p
// (uniform 33 tile-computes/block). One K/V staging shared by both q-tiles.
// exp2-domain softmax; mask only on diagonal tiles; Q frags hoisted.
// ---------------------------------------------------------------------------
#define AT_PAD 72
#define LOG2E 1.4426950408889634f

__device__ __forceinline__ void attn_tile_step(
        short8 aq0, short8 aq1,
        ushort (*__restrict__ Ks)[AT_PAD],
        ushort (*__restrict__ Vt)[AT_PAD],
        ushort (*__restrict__ Ps)[AT_PAD],
        float* m_r, float* l_r, floatx4* acc,
        int q0, int kt, bool domask,
        float qs2, float slope2, const float* skb,
        int w, int quad, int l16) {
    // ---- scores: S[16q x 64k] for this wave ----
    floatx4 sfrag[4];
#pragma unroll
    for (int kb = 0; kb < 4; kb++) {
        const int kcol = kb * 16 + l16;
        short8 bk0 = *(const short8*)&Ks[kcol][quad * 8];
        short8 bk1 = *(const short8*)&Ks[kcol][32 + quad * 8];
        floatx4 s = (floatx4){0.f, 0.f, 0.f, 0.f};
        s = __builtin_amdgcn_mfma_f32_16x16x32_bf16(aq0, bk0, s, 0, 0, 0);
        s = __builtin_amdgcn_mfma_f32_16x16x32_bf16(aq1, bk1, s, 0, 0, 0);
        sfrag[kb] = s;
    }

    // ---- ALiBi + (diagonal-only) mask + online softmax, exp2 domain ----
    const float ktb = (float)(kt * 64);
#pragma unroll
    for (int r = 0; r < 4; r++) {
        const int q = q0 + w * 16 + quad * 4 + r;
        const float rowc = slope2 * ((float)q - ktb);
        float sv[4];
        float rm = -INFINITY;
#pragma unroll
        for (int kb = 0; kb < 4; kb++) {
            float s = fmaf(sfrag[kb][r], qs2, rowc) - skb[kb];
            if (domask) {
                const int k = kt * 64 + kb * 16 + l16;
                s = (k <= q) ? s : -INFINITY;
            }
            sv[kb] = s;
            rm = fmaxf(rm, s);
        }
#pragma unroll
        for (int o = 8; o >= 1; o >>= 1) rm = fmaxf(rm, __shfl_xor(rm, o));
        const float mnew = fmaxf(m_r[r], rm);
        const float corr = exp2f(m_r[r] - mnew);
        float rs = 0.f;
#pragma unroll
        for (int kb = 0; kb < 4; kb++) {
            const float pv = exp2f(sv[kb] - mnew);
            rs += pv;
            Ps[w * 16 + quad * 4 + r][kb * 16 + l16] = f2b(pv);
        }
#pragma unroll
        for (int o = 8; o >= 1; o >>= 1) rs += __shfl_xor(rs, o);
        l_r[r] = l_r[r] * corr + rs;
        m_r[r] = mnew;
#pragma unroll
        for (int db = 0; db < 4; db++) acc[db][r] *= corr;
    }

    // ---- PV (Ps rows are wave-private: no barrier needed) ----
    short8 ap0 = *(const short8*)&Ps[w * 16 + l16][quad * 8];
    short8 ap1 = *(const short8*)&Ps[w * 16 + l16][32 + quad * 8];
#pragma unroll
    for (int db = 0; db < 4; db++) {
        short8 bv0 = *(const short8*)&Vt[db * 16 + l16][quad * 8];
        short8 bv1 = *(const short8*)&Vt[db * 16 + l16][32 + quad * 8];
        acc[db] = __builtin_amdgcn_mfma_f32_16x16x32_bf16(ap0, bv0, acc[db], 0, 0, 0);
        acc[db] = __builtin_amdgcn_mfma_f32_16x16x32_bf16(ap1, bv1, acc[db], 0, 0, 0);
    }
}

__global__ __launch_bounds__(256) void attn_mfma_kernel(
        const ushort* __restrict__ qkv, ushort* __restrict__ y, int B, int T) {
    const int C3 = 3 * N_EMBD;
    const int NT = T / 64;                 // 32
    const int p  = blockIdx.x;             // 0..NT/2-1
    const int h  = blockIdx.y;
    const int b  = blockIdx.z;
    const int qtA = NT - 1 - p;            // big tile
    const int qtB = p;                     // small tile
    const int tid  = threadIdx.x;
    const int lane = tid & 63;
    const int w    = tid >> 6;
    const int quad = lane >> 4;
    const int l16  = lane & 15;

    __shared__ ushort QsA[64][AT_PAD];
    __shared__ ushort QsB[64][AT_PAD];
    __shared__ ushort Ks[64][AT_PAD];
    __shared__ ushort Vt[64][AT_PAD];
    __shared__ ushort Ps[64][AT_PAD];

    const float slope  = exp2f(-0.5f * (float)(h + 1));
    const float slope2 = slope * LOG2E;
    const float qs2    = 0.125f * LOG2E;
    float skb[4];
#pragma unroll
    for (int kb = 0; kb < 4; kb++) skb[kb] = slope2 * (float)(kb * 16 + l16);

    const int q0A = qtA * 64, q0B = qtB * 64;
    const size_t hb = (size_t)b * T * C3 + (size_t)h * HEAD_D;

    // stage both Q tiles
#pragma unroll
    for (int i = 0; i < 4; i++) {
        int idx = tid + i * 256;
        int row = idx >> 4, d0 = (idx & 15) * 4;
        *(ushort4*)&QsA[row][d0] =
            *(const ushort4*)&qkv[hb + (size_t)(q0A + row) * C3 + d0];
        *(ushort4*)&QsB[row][d0] =
            *(const ushort4*)&qkv[hb + (size_t)(q0B + row) * C3 + d0];
    }
    __syncthreads();

    // hoist Q fragments (constant across kt)
    const int mrow = w * 16 + l16;
    short8 aqA0 = *(const short8*)&QsA[mrow][quad * 8];
    short8 aqA1 = *(const short8*)&QsA[mrow][32 + quad * 8];
    short8 aqB0 = *(const short8*)&QsB[mrow][quad * 8];
    short8 aqB1 = *(const short8*)&QsB[mrow][32 + quad * 8];

    float mA[4], lA[4], mB[4], lB[4];
    floatx4 accA[4], accB[4];
#pragma unroll
    for (int r = 0; r < 4; r++) {
        mA[r] = -INFINITY; lA[r] = 0.f;
        mB[r] = -INFINITY; lB[r] = 0.f;
        accA[r] = (floatx4){0.f, 0.f, 0.f, 0.f};
        accB[r] = (floatx4){0.f, 0.f, 0.f, 0.f};
    }

    for (int kt = 0; kt <= qtA; kt++) {
        // ---- stage K (row-major) and V (transposed), shared by both tiles ----
#pragma unroll
        for (int i = 0; i < 4; i++) {
            int idx = tid + i * 256;
            int row = idx >> 4, d0 = (idx & 15) * 4;
            const size_t src = hb + (size_t)(kt * 64 + row) * C3 + d0;
            *(ushort4*)&Ks[row][d0] = *(const ushort4*)&qkv[src + N_EMBD];
            ushort4 vv = *(const ushort4*)&qkv[src + 2 * N_EMBD];
            Vt[d0 + 0][row] = vv.x;
            Vt[d0 + 1][row] = vv.y;
            Vt[d0 + 2][row] = vv.z;
            Vt[d0 + 3][row] = vv.w;
        }
        __syncthreads();

        attn_tile_step(aqA0, aqA1, Ks, Vt, Ps, mA, lA, accA,
                       q0A, kt, kt == qtA, qs2, slope2, skb, w, quad, l16);
        if (kt <= qtB)
            attn_tile_step(aqB0, aqB1, Ks, Vt, Ps, mB, lB, accB,
                           q0B, kt, kt == qtB, qs2, slope2, skb, w, quad, l16);
        __syncthreads();
    }

    // ---- epilogue ----
#pragma unroll
    for (int r = 0; r < 4; r++) {
        const int qa = q0A + w * 16 + quad * 4 + r;
        const int qb = q0B + w * 16 + quad * 4 + r;
        const float ia = 1.f / lA[r];
        const float ib = 1.f / lB[r];
#pragma unroll
        for (int db = 0; db < 4; db++) {
            y[((size_t)b * T + qa) * N_EMBD + h * HEAD_D + db * 16 + l16] =
                f2b(accA[db][r] * ia);
            y[((size_t)b * T + qb) * N_EMBD + h * HEAD_D + db * 16 + l16] =
                f2b(accB[db][r] * ib);
        }
    }
}

// ---------------------------------------------------------------------------
extern "C" void kernel_launch(void* const* d_in, const int* in_sizes, int n_in,
                              void* d_out, int out_size, void* d_ws, size_t ws_size,
                              hipStream_t stream) {
    const int B = 2, T = 2048, C = N_EMBD;
    const int M = B * T;

    const float* x      = (const float*)d_in[0];
    const float* ln1_w  = (const float*)d_in[1];
    const float* ln1_b  = (const float*)d_in[2];
    const float* w_qkv  = (const float*)d_in[3];
    const float* b_qkv  = (const float*)d_in[4];
    const float* w_proj = (const float*)d_in[5];
    const float* b_proj = (const float*)d_in[6];
    const float* ln2_w  = (const float*)d_in[7];
    const float* ln2_b  = (const float*)d_in[8];
    const float* w_fc   = (const float*)d_in[9];
    const float* b_fc   = (const float*)d_in[10];
    const float* w_fc2  = (const float*)d_in[11];
    const float* b_fc2  = (const float*)d_in[12];
    float* out = (float*)d_out;

    char* ws = (char*)d_ws;
    size_t off = 0;
    ushort* wt_qkv  = (ushort*)(ws + off); off += (size_t)3 * C * C * 2;
    ushort* wt_proj = (ushort*)(ws + off); off += (size_t)C * C * 2;
    ushort* wt_fc   = (ushort*)(ws + off); off += (size_t)4 * C * C * 2;
    ushort* wt_fc2  = (ushort*)(ws + off); off += (size_t)4 * C * C * 2;
    ushort* h16     = (ushort*)(ws + off); off += (size_t)M * C * 2;
    ushort* qkv16   = (ushort*)(ws + off); off += (size_t)M * 3 * C * 2;
    ushort* y16     = (ushort*)(ws + off); off += (size_t)M * C * 2;
    ushort* fc16    = (ushort*)(ws + off); off += (size_t)M * 4 * C * 2;

    // 0. weight transpose+convert
    convtrans_kernel<<<dim3(3 * C / 32, C / 32), 256, 0, stream>>>(w_qkv, wt_qkv, C, 3 * C);
    convtrans_kernel<<<dim3(C / 32, C / 32), 256, 0, stream>>>(w_proj, wt_proj, C, C);
    convtrans_kernel<<<dim3(4 * C / 32, C / 32), 256, 0, stream>>>(w_fc, wt_fc, C, 4 * C);
    convtrans_kernel<<<dim3(C / 32, 4 * C / 32), 256, 0, stream>>>(w_fc2, wt_fc2, 4 * C, C);

    // 1. h = LN1(x) -> bf16
    ln_kernel<<<M, 256, 0, stream>>>(x, ln1_w, ln1_b, h16, C);

    // 2. qkv = h @ w_qkv + b_qkv -> bf16
    gemm_bf16_kernel<<<dim3(3 * C / 128, M / 128), 256, 0, stream>>>(
        h16, wt_qkv, b_qkv, nullptr, nullptr, qkv16, M, 3 * C, C, 0);

    // 3. y = flash ALiBi attention (triangle-paired) -> bf16
    attn_mfma_kernel<<<dim3(T / 128, N_HEADC, B), 256, 0, stream>>>(
        qkv16, y16, B, T);

    // 4. x1 = x + y @ w_proj + b_proj -> d_out (fp32)
    gemm_bf16_kernel<<<dim3(C / 128, M / 128), 256, 0, stream>>>(
        y16, wt_proj, b_proj, x, out, nullptr, M, C, C, 0);

    // 5. h = LN2(x1) -> bf16
    ln_kernel<<<M, 256, 0, stream>>>(out, ln2_w, ln2_b, h16, C);

    // 6. fc = gelu(h @ w_fc + b_fc) -> bf16
    gemm_bf16_kernel<<<dim3(4 * C / 128, M / 128), 256, 0, stream>>>(
        h16, wt_fc, b_fc, nullptr, nullptr, fc16, M, 4 * C, C, 1);

    // 7. out = x1 + fc @ w_fc2 + b_fc2 -> d_out (fp32)
    gemm_bf16_kernel<<<dim3(C / 128, M / 128), 256, 0, stream>>>(
        fc16, wt_fc2, b_fc2, out, out, nullptr, M, C, 4 * C, 0);
}